// Round 2
// 219.976 us; speedup vs baseline: 1.0013x; 1.0013x over previous
//
#include <hip/hip_runtime.h>

// LWTA over groups of POOL_SIZE=4 consecutive fp32 elements.
// out[i] = in[i] if i is the FIRST max within its group of 4, else 0.
// Input: 4096x8192 fp32 (flat 33,554,432 elems -> 8,388,608 float4 groups).
//
// Memory-bound streaming op (268 MB HBM traffic, roofline ~43 us @ 6.3 TB/s).
// Capped grid + grid-stride loop (Guideline 11): 2048 blocks x 256 threads,
// each thread streams 16 float4s -> multiple independent loads in flight per
// wave, amortized workgroup dispatch cost. Non-temporal loads/stores via
// native clang vector type (HIP_vector_type is a struct and is rejected by
// __builtin_nontemporal_*).

typedef float f32x4 __attribute__((ext_vector_type(4)));

__global__ __launch_bounds__(256) void lwta_kernel(const f32x4* __restrict__ in,
                                                   f32x4* __restrict__ out,
                                                   int n_groups) {
    const int stride = gridDim.x * blockDim.x;
    int g = blockIdx.x * blockDim.x + threadIdx.x;

    for (; g < n_groups; g += stride) {
        f32x4 v = __builtin_nontemporal_load(&in[g]);

        // First-max-index semantics (matches jnp.argmax): strict > keeps earliest.
        float m = v.x;
        int w = 0;
        if (v.y > m) { m = v.y; w = 1; }
        if (v.z > m) { m = v.z; w = 2; }
        if (v.w > m) { m = v.w; w = 3; }

        f32x4 o;
        o.x = (w == 0) ? v.x : 0.0f;
        o.y = (w == 1) ? v.y : 0.0f;
        o.z = (w == 2) ? v.z : 0.0f;
        o.w = (w == 3) ? v.w : 0.0f;

        __builtin_nontemporal_store(o, &out[g]);
    }
}

extern "C" void kernel_launch(void* const* d_in, const int* in_sizes, int n_in,
                              void* d_out, int out_size, void* d_ws, size_t ws_size,
                              hipStream_t stream) {
    const f32x4* in = (const f32x4*)d_in[0];
    f32x4* out = (f32x4*)d_out;

    int n_elems = in_sizes[0];          // 4096*8192 = 33,554,432
    int n_groups = n_elems / 4;         // 8,388,608 groups, one float4 each

    const int block = 256;
    int grid = (n_groups + block - 1) / block;
    if (grid > 2048) grid = 2048;       // cap + grid-stride (memory-bound op)

    lwta_kernel<<<grid, block, 0, stream>>>(in, out, n_groups);
}